// Round 1
// baseline (249.323 us; speedup 1.0000x reference)
//
#include <hip/hip_runtime.h>

#define BATCH 8
#define NPTS 2048
#define ROWS_PER_BLOCK 16
#define ROWGROUPS (NPTS / ROWS_PER_BLOCK)        // 128 row-groups per batch
#define BLOCKS_PER_BATCH (ROWGROUPS * 2)         // 256: each row-group split into two 1024-col halves

// clang ext_vector (HIP's float4 is a struct and rejects __builtin_nontemporal_load)
typedef float f4 __attribute__((ext_vector_type(4)));

// ---------------- kernel 1: streaming pass over M (column-accumulation form) ----
// S[d,e] = sum_k P[k,d] * T[k,e],  T[k,e] = sum_n M[n,k] * Q[n,e]
// sum_matched[d] = sum_k P[k,d] * colsum[k]
// Each block owns ROWS_PER_BLOCK rows x 1024 columns (one half). Thread t owns
// one float4 column group -> 16 accumulator floats (vs 32 in the 2-stream
// version), so __launch_bounds__(256,8) holds VGPR<=64 -> 8 waves/SIMD.
// Explicit 1-ahead prefetch rotation keeps a load in flight across each FMA
// burst; nontemporal hint since M is read exactly once.
__global__ void __launch_bounds__(256, 8) cross_cov_kernel(
        const float* __restrict__ P, const float* __restrict__ Q,
        const float* __restrict__ M, float* __restrict__ ws) {
    __shared__ float sQ[ROWS_PER_BLOCK * 3];
    __shared__ float partial[4][12];

    const int b = blockIdx.x >> 8;           // BLOCKS_PER_BATCH = 256
    const int blkInB = blockIdx.x & 255;
    const int rowGroup = blkInB >> 1;
    const int colHalf = blkInB & 1;
    const int n0 = rowGroup * ROWS_PER_BLOCK;
    const int colBase = colHalf * 1024;

    const float* Pb = P + b * NPTS * 3;
    const float* Qb = Q + b * NPTS * 3;
    const float* Mb = M + (size_t)b * NPTS * NPTS;

    const int t = threadIdx.x;
    if (t < ROWS_PER_BLOCK * 3) sQ[t] = Qb[n0 * 3 + t];
    __syncthreads();

    // accumulators: 4 cols x (T[3] + colsum) = 16 regs
    float T[4][3] = {};
    float cs[4] = {};

    const f4* Mrow = reinterpret_cast<const f4*>(Mb + (size_t)n0 * NPTS + colBase) + t;

    f4 c = __builtin_nontemporal_load(Mrow);
#pragma unroll
    for (int r = 0; r < ROWS_PER_BLOCK; ++r) {
        f4 nx = c;
        if (r + 1 < ROWS_PER_BLOCK)            // compile-time resolved (full unroll)
            nx = __builtin_nontemporal_load(Mrow + (size_t)(r + 1) * 512);  // row stride = 2048 f = 512 f4
        const float q0 = sQ[r * 3 + 0];
        const float q1 = sQ[r * 3 + 1];
        const float q2 = sQ[r * 3 + 2];
        T[0][0] += c.x * q0; T[0][1] += c.x * q1; T[0][2] += c.x * q2; cs[0] += c.x;
        T[1][0] += c.y * q0; T[1][1] += c.y * q1; T[1][2] += c.y * q2; cs[1] += c.y;
        T[2][0] += c.z * q0; T[2][1] += c.z * q1; T[2][2] += c.z * q2; cs[2] += c.z;
        T[3][0] += c.w * q0; T[3][1] += c.w * q1; T[3][2] += c.w * q2; cs[3] += c.w;
        c = nx;
    }

    // fold in P: columns k0 = colBase + 4t .. +3 (12 consecutive floats)
    float acc[12];
#pragma unroll
    for (int i = 0; i < 12; ++i) acc[i] = 0.0f;
    {
        const int k0 = colBase + 4 * t;
        const float* p0 = Pb + k0 * 3;
#pragma unroll
        for (int j = 0; j < 4; ++j) {
            const float pd0 = p0[j * 3 + 0], pd1 = p0[j * 3 + 1], pd2 = p0[j * 3 + 2];
#pragma unroll
            for (int e = 0; e < 3; ++e) {
                acc[0 + e] += pd0 * T[j][e];
                acc[3 + e] += pd1 * T[j][e];
                acc[6 + e] += pd2 * T[j][e];
            }
            acc[9]  += pd0 * cs[j];
            acc[10] += pd1 * cs[j];
            acc[11] += pd2 * cs[j];
        }
    }

    // block reduction of 12 values: wave butterfly, then LDS across 4 waves
#pragma unroll
    for (int off = 32; off > 0; off >>= 1) {
#pragma unroll
        for (int i = 0; i < 12; ++i) acc[i] += __shfl_xor(acc[i], off);
    }
    const int wave = t >> 6;
    const int lane = t & 63;
    if (lane == 0) {
#pragma unroll
        for (int i = 0; i < 12; ++i) partial[wave][i] = acc[i];
    }
    __syncthreads();
    if (t < 12) {
        float v = partial[0][t] + partial[1][t] + partial[2][t] + partial[3][t];
        ws[(size_t)blockIdx.x * 12 + t] = v;   // per-block partial, no atomics
    }
}

// ---------------- kernel 2: reduce partials + means + 3x3 polar -> R, t ----------
__global__ void __launch_bounds__(256) finalize_kernel(
        const float* __restrict__ P, const float* __restrict__ Q,
        const float* __restrict__ ws, float* __restrict__ out) {
    const int b = blockIdx.x;
    const float* Pb = P + b * NPTS * 3;
    const float* Qb = Q + b * NPTS * 3;
    const int t = threadIdx.x;
    const int wave = t >> 6;
    const int lane = t & 63;

    __shared__ float redS[4][12];
    __shared__ float red[4][6];

    // ---- reduce the 256 per-block partials of this batch (all 256 threads) ----
    {
        const f4* p4 = reinterpret_cast<const f4*>(
            ws + ((size_t)b * BLOCKS_PER_BATCH + t) * 12);
        f4 a = p4[0], c = p4[1], d = p4[2];
        float v[12] = { a.x, a.y, a.z, a.w, c.x, c.y, c.z, c.w, d.x, d.y, d.z, d.w };
#pragma unroll
        for (int off = 32; off > 0; off >>= 1) {
#pragma unroll
            for (int i = 0; i < 12; ++i) v[i] += __shfl_xor(v[i], off);
        }
        if (lane == 0) {
#pragma unroll
            for (int i = 0; i < 12; ++i) redS[wave][i] = v[i];
        }
    }

    // ---- P/Q column sums (all 256 threads) ----
    float px = 0, py = 0, pz = 0, qx = 0, qy = 0, qz = 0;
    for (int k = t; k < NPTS; k += 256) {
        px += Pb[k * 3 + 0]; py += Pb[k * 3 + 1]; pz += Pb[k * 3 + 2];
        qx += Qb[k * 3 + 0]; qy += Qb[k * 3 + 1]; qz += Qb[k * 3 + 2];
    }
#pragma unroll
    for (int off = 32; off > 0; off >>= 1) {
        px += __shfl_xor(px, off); py += __shfl_xor(py, off); pz += __shfl_xor(pz, off);
        qx += __shfl_xor(qx, off); qy += __shfl_xor(qy, off); qz += __shfl_xor(qz, off);
    }
    if (lane == 0) {
        red[wave][0] = px; red[wave][1] = py; red[wave][2] = pz;
        red[wave][3] = qx; red[wave][4] = qy; red[wave][5] = qz;
    }
    __syncthreads();

    if (t == 0) {
        double sp[3], sq[3];
        for (int i = 0; i < 3; ++i) {
            sp[i] = (double)red[0][i] + red[1][i] + red[2][i] + red[3][i];
            sq[i] = (double)red[0][3 + i] + red[1][3 + i] + red[2][3 + i] + red[3][3 + i];
        }
        double w[12];
        for (int i = 0; i < 12; ++i)
            w[i] = (double)redS[0][i] + (double)redS[1][i]
                 + (double)redS[2][i] + (double)redS[3][i];

        // S[d][e] = S_raw[d][e] - sum_matched[d]*sum_Q[e]/N
        double Sm[9];
        for (int d = 0; d < 3; ++d)
            for (int e = 0; e < 3; ++e)
                Sm[d * 3 + e] = w[d * 3 + e] - w[9 + d] * sq[e] / (double)NPTS;

        // R = V U^T = orthogonal polar factor of A = S^T (scaled Newton).
        // Scaled Newton converges quadratically; 12 iters >> enough for a
        // well-conditioned random 3x3 (was 20 -> shaves serial f64 latency).
        double X[9];
        for (int i = 0; i < 3; ++i)
            for (int j = 0; j < 3; ++j)
                X[i * 3 + j] = Sm[j * 3 + i];
        for (int iter = 0; iter < 12; ++iter) {
            double a0 = X[0], a1 = X[1], a2 = X[2];
            double a3 = X[3], a4 = X[4], a5 = X[5];
            double a6 = X[6], a7 = X[7], a8 = X[8];
            double c0 = a4 * a8 - a5 * a7;
            double c1 = a5 * a6 - a3 * a8;
            double c2 = a3 * a7 - a4 * a6;
            double det = a0 * c0 + a1 * c1 + a2 * c2;
            double invdet = 1.0 / det;
            double inv[9];
            inv[0] = c0 * invdet; inv[1] = (a2 * a7 - a1 * a8) * invdet; inv[2] = (a1 * a5 - a2 * a4) * invdet;
            inv[3] = c1 * invdet; inv[4] = (a0 * a8 - a2 * a6) * invdet; inv[5] = (a2 * a3 - a0 * a5) * invdet;
            inv[6] = c2 * invdet; inv[7] = (a1 * a6 - a0 * a7) * invdet; inv[8] = (a0 * a4 - a1 * a3) * invdet;
            double fx = 0, fi = 0;
            for (int i = 0; i < 9; ++i) { fx += X[i] * X[i]; fi += inv[i] * inv[i]; }
            double g = sqrt(sqrt(fi / fx));
            double Xn[9];
            for (int i = 0; i < 3; ++i)
                for (int j = 0; j < 3; ++j)
                    Xn[i * 3 + j] = 0.5 * (g * X[i * 3 + j] + inv[j * 3 + i] / g);
            for (int i = 0; i < 9; ++i) X[i] = Xn[i];
        }
        for (int i = 0; i < 9; ++i) out[b * 9 + i] = (float)X[i];
        double mpx = sp[0] / NPTS, mpy = sp[1] / NPTS, mpz = sp[2] / NPTS;
        for (int d = 0; d < 3; ++d) {
            double td = sq[d] / NPTS - (X[d * 3 + 0] * mpx + X[d * 3 + 1] * mpy + X[d * 3 + 2] * mpz);
            out[BATCH * 9 + b * 3 + d] = (float)td;
        }
    }
}

extern "C" void kernel_launch(void* const* d_in, const int* in_sizes, int n_in,
                              void* d_out, int out_size, void* d_ws, size_t ws_size,
                              hipStream_t stream) {
    const float* P = (const float*)d_in[0];   // Ppc [8,2048,3] f32
    const float* Q = (const float*)d_in[1];   // Qpc [8,2048,3] f32
    const float* M = (const float*)d_in[2];   // M   [8,2048,2048] f32
    float* out = (float*)d_out;               // R [8,3,3] ++ t [8,3] = 96 f32
    float* ws = (float*)d_ws;                 // per-block partials: 2048*12 f32 = 96 KB

    cross_cov_kernel<<<BATCH * BLOCKS_PER_BATCH, 256, 0, stream>>>(P, Q, M, ws);
    finalize_kernel<<<BATCH, 256, 0, stream>>>(P, Q, ws, out);
}

// Round 2
// 197.598 us; speedup vs baseline: 1.2618x; 1.2618x over previous
//
#include <hip/hip_runtime.h>

#define BATCH 8
#define NPTS 2048
#define BLOCKS_PER_BATCH 128
#define ROWS_PER_BLOCK 16   // NPTS / BLOCKS_PER_BATCH

// clang ext_vector (HIP's float4 is a struct; __builtin_nontemporal_load needs a scalar/vector type)
typedef float f4 __attribute__((ext_vector_type(4)));

// ---------------- kernel 1: streaming pass over M (column-accumulation form) ----
// S[d,e] = sum_k P[k,d] * T[k,e],  T[k,e] = sum_n M[n,k] * Q[n,e]
// sum_matched[d] = sum_k P[k,d] * colsum[k]
// Each block owns ROWS_PER_BLOCK rows x all 2048 columns. Thread t owns float4
// column groups {t, t+256} (512 float4 cols total). Zero cross-lane traffic in
// the hot loop; one 12-value block reduction at the end; partials to ws.
// NOTE (R1 post-mortem): do NOT force min-waves via __launch_bounds__(256,8) —
// it capped VGPR at 64, spilled ~235 B/thread to scratch (WRITE_SIZE 123 MB,
// 3.0 TB/s effective). Natural allocation (~96 VGPR, 4 waves/SIMD) is spill-free.
__global__ void __launch_bounds__(256) cross_cov_kernel(
        const float* __restrict__ P, const float* __restrict__ Q,
        const float* __restrict__ M, float* __restrict__ ws) {
    __shared__ float sQ[ROWS_PER_BLOCK * 3];
    __shared__ float partial[4][12];

    const int b = blockIdx.x >> 7;           // BLOCKS_PER_BATCH = 128
    const int blkInB = blockIdx.x & 127;
    const int n0 = blkInB * ROWS_PER_BLOCK;
    const float* Pb = P + b * NPTS * 3;
    const float* Qb = Q + b * NPTS * 3;
    const float* Mb = M + (size_t)b * NPTS * NPTS;

    const int t = threadIdx.x;
    if (t < ROWS_PER_BLOCK * 3) sQ[t] = Qb[n0 * 3 + t];
    __syncthreads();

    // accumulators: 2 column groups x 4 cols x (T[3] + colsum) = 32 regs
    float T0[4][3] = {}, T1[4][3] = {};
    float cs0[4] = {}, cs1[4] = {};

    const f4* Mrow0 = reinterpret_cast<const f4*>(Mb + (size_t)n0 * NPTS) + t;
    const f4* Mrow1 = Mrow0 + 256;

#pragma unroll 4
    for (int r = 0; r < ROWS_PER_BLOCK; ++r) {
        // M is read exactly once -> non-temporal hint (don't pollute L2/L3)
        const f4 m0 = __builtin_nontemporal_load(Mrow0 + (size_t)r * 512);  // row stride = 2048 f = 512 f4
        const f4 m1 = __builtin_nontemporal_load(Mrow1 + (size_t)r * 512);
        const float q0 = sQ[r * 3 + 0];
        const float q1 = sQ[r * 3 + 1];
        const float q2 = sQ[r * 3 + 2];
        T0[0][0] += m0.x * q0; T0[0][1] += m0.x * q1; T0[0][2] += m0.x * q2; cs0[0] += m0.x;
        T0[1][0] += m0.y * q0; T0[1][1] += m0.y * q1; T0[1][2] += m0.y * q2; cs0[1] += m0.y;
        T0[2][0] += m0.z * q0; T0[2][1] += m0.z * q1; T0[2][2] += m0.z * q2; cs0[2] += m0.z;
        T0[3][0] += m0.w * q0; T0[3][1] += m0.w * q1; T0[3][2] += m0.w * q2; cs0[3] += m0.w;
        T1[0][0] += m1.x * q0; T1[0][1] += m1.x * q1; T1[0][2] += m1.x * q2; cs1[0] += m1.x;
        T1[1][0] += m1.y * q0; T1[1][1] += m1.y * q1; T1[1][2] += m1.y * q2; cs1[1] += m1.y;
        T1[2][0] += m1.z * q0; T1[2][1] += m1.z * q1; T1[2][2] += m1.z * q2; cs1[2] += m1.z;
        T1[3][0] += m1.w * q0; T1[3][1] += m1.w * q1; T1[3][2] += m1.w * q2; cs1[3] += m1.w;
    }

    // fold in P: columns k0 = 4t .. 4t+3 and k1 = 4(t+256) ..
    float acc[12];
#pragma unroll
    for (int i = 0; i < 12; ++i) acc[i] = 0.0f;
    {
        const int k0 = 4 * t;
        const int k1 = 4 * (t + 256);
        const float* p0 = Pb + k0 * 3;     // 12 consecutive floats, 16B-aligned
        const float* p1 = Pb + k1 * 3;
#pragma unroll
        for (int j = 0; j < 4; ++j) {
            const float pd0 = p0[j * 3 + 0], pd1 = p0[j * 3 + 1], pd2 = p0[j * 3 + 2];
#pragma unroll
            for (int e = 0; e < 3; ++e) {
                acc[0 + e] += pd0 * T0[j][e];
                acc[3 + e] += pd1 * T0[j][e];
                acc[6 + e] += pd2 * T0[j][e];
            }
            acc[9]  += pd0 * cs0[j];
            acc[10] += pd1 * cs0[j];
            acc[11] += pd2 * cs0[j];
        }
#pragma unroll
        for (int j = 0; j < 4; ++j) {
            const float pd0 = p1[j * 3 + 0], pd1 = p1[j * 3 + 1], pd2 = p1[j * 3 + 2];
#pragma unroll
            for (int e = 0; e < 3; ++e) {
                acc[0 + e] += pd0 * T1[j][e];
                acc[3 + e] += pd1 * T1[j][e];
                acc[6 + e] += pd2 * T1[j][e];
            }
            acc[9]  += pd0 * cs1[j];
            acc[10] += pd1 * cs1[j];
            acc[11] += pd2 * cs1[j];
        }
    }

    // block reduction of 12 values: wave butterfly (once per block), then LDS
#pragma unroll
    for (int off = 32; off > 0; off >>= 1) {
#pragma unroll
        for (int i = 0; i < 12; ++i) acc[i] += __shfl_xor(acc[i], off);
    }
    const int wave = t >> 6;
    const int lane = t & 63;
    if (lane == 0) {
#pragma unroll
        for (int i = 0; i < 12; ++i) partial[wave][i] = acc[i];
    }
    __syncthreads();
    if (t < 12) {
        float v = partial[0][t] + partial[1][t] + partial[2][t] + partial[3][t];
        ws[(size_t)blockIdx.x * 12 + t] = v;   // per-block partial, no atomics
    }
}

// ---------------- kernel 2: reduce partials + means + 3x3 polar -> R, t ----------
__global__ void __launch_bounds__(256) finalize_kernel(
        const float* __restrict__ P, const float* __restrict__ Q,
        const float* __restrict__ ws, float* __restrict__ out) {
    const int b = blockIdx.x;
    const float* Pb = P + b * NPTS * 3;
    const float* Qb = Q + b * NPTS * 3;
    const int t = threadIdx.x;
    const int wave = t >> 6;
    const int lane = t & 63;

    __shared__ float redS[2][12];
    __shared__ float red[4][6];

    // ---- reduce the 128 per-block partials of this batch (threads 0..127) ----
    if (t < BLOCKS_PER_BATCH) {
        const f4* p4 = reinterpret_cast<const f4*>(
            ws + ((size_t)b * BLOCKS_PER_BATCH + t) * 12);
        f4 a = p4[0], c = p4[1], d = p4[2];
        float v[12] = { a.x, a.y, a.z, a.w, c.x, c.y, c.z, c.w, d.x, d.y, d.z, d.w };
#pragma unroll
        for (int off = 32; off > 0; off >>= 1) {
#pragma unroll
            for (int i = 0; i < 12; ++i) v[i] += __shfl_xor(v[i], off);
        }
        if (lane == 0) {
#pragma unroll
            for (int i = 0; i < 12; ++i) redS[wave][i] = v[i];
        }
    }

    // ---- P/Q column sums (all 256 threads) ----
    float px = 0, py = 0, pz = 0, qx = 0, qy = 0, qz = 0;
    for (int k = t; k < NPTS; k += 256) {
        px += Pb[k * 3 + 0]; py += Pb[k * 3 + 1]; pz += Pb[k * 3 + 2];
        qx += Qb[k * 3 + 0]; qy += Qb[k * 3 + 1]; qz += Qb[k * 3 + 2];
    }
#pragma unroll
    for (int off = 32; off > 0; off >>= 1) {
        px += __shfl_xor(px, off); py += __shfl_xor(py, off); pz += __shfl_xor(pz, off);
        qx += __shfl_xor(qx, off); qy += __shfl_xor(qy, off); qz += __shfl_xor(qz, off);
    }
    if (lane == 0) {
        red[wave][0] = px; red[wave][1] = py; red[wave][2] = pz;
        red[wave][3] = qx; red[wave][4] = qy; red[wave][5] = qz;
    }
    __syncthreads();

    if (t == 0) {
        double sp[3], sq[3];
        for (int i = 0; i < 3; ++i) {
            sp[i] = (double)red[0][i] + red[1][i] + red[2][i] + red[3][i];
            sq[i] = (double)red[0][3 + i] + red[1][3 + i] + red[2][3 + i] + red[3][3 + i];
        }
        double w[12];
        for (int i = 0; i < 12; ++i) w[i] = (double)redS[0][i] + (double)redS[1][i];

        // S[d][e] = S_raw[d][e] - sum_matched[d]*sum_Q[e]/N
        double Sm[9];
        for (int d = 0; d < 3; ++d)
            for (int e = 0; e < 3; ++e)
                Sm[d * 3 + e] = w[d * 3 + e] - w[9 + d] * sq[e] / (double)NPTS;

        // R = V U^T = orthogonal polar factor of A = S^T (scaled Newton).
        // 12 iters: quadratic convergence, verified absmax=0 in R1.
        double X[9];
        for (int i = 0; i < 3; ++i)
            for (int j = 0; j < 3; ++j)
                X[i * 3 + j] = Sm[j * 3 + i];
        for (int iter = 0; iter < 12; ++iter) {
            double a0 = X[0], a1 = X[1], a2 = X[2];
            double a3 = X[3], a4 = X[4], a5 = X[5];
            double a6 = X[6], a7 = X[7], a8 = X[8];
            double c0 = a4 * a8 - a5 * a7;
            double c1 = a5 * a6 - a3 * a8;
            double c2 = a3 * a7 - a4 * a6;
            double det = a0 * c0 + a1 * c1 + a2 * c2;
            double invdet = 1.0 / det;
            double inv[9];
            inv[0] = c0 * invdet; inv[1] = (a2 * a7 - a1 * a8) * invdet; inv[2] = (a1 * a5 - a2 * a4) * invdet;
            inv[3] = c1 * invdet; inv[4] = (a0 * a8 - a2 * a6) * invdet; inv[5] = (a2 * a3 - a0 * a5) * invdet;
            inv[6] = c2 * invdet; inv[7] = (a1 * a6 - a0 * a7) * invdet; inv[8] = (a0 * a4 - a1 * a3) * invdet;
            double fx = 0, fi = 0;
            for (int i = 0; i < 9; ++i) { fx += X[i] * X[i]; fi += inv[i] * inv[i]; }
            double g = sqrt(sqrt(fi / fx));
            double Xn[9];
            for (int i = 0; i < 3; ++i)
                for (int j = 0; j < 3; ++j)
                    Xn[i * 3 + j] = 0.5 * (g * X[i * 3 + j] + inv[j * 3 + i] / g);
            for (int i = 0; i < 9; ++i) X[i] = Xn[i];
        }
        for (int i = 0; i < 9; ++i) out[b * 9 + i] = (float)X[i];
        double mpx = sp[0] / NPTS, mpy = sp[1] / NPTS, mpz = sp[2] / NPTS;
        for (int d = 0; d < 3; ++d) {
            double td = sq[d] / NPTS - (X[d * 3 + 0] * mpx + X[d * 3 + 1] * mpy + X[d * 3 + 2] * mpz);
            out[BATCH * 9 + b * 3 + d] = (float)td;
        }
    }
}

extern "C" void kernel_launch(void* const* d_in, const int* in_sizes, int n_in,
                              void* d_out, int out_size, void* d_ws, size_t ws_size,
                              hipStream_t stream) {
    const float* P = (const float*)d_in[0];   // Ppc [8,2048,3] f32
    const float* Q = (const float*)d_in[1];   // Qpc [8,2048,3] f32
    const float* M = (const float*)d_in[2];   // M   [8,2048,2048] f32
    float* out = (float*)d_out;               // R [8,3,3] ++ t [8,3] = 96 f32
    float* ws = (float*)d_ws;                 // per-block partials: 1024*12 f32

    cross_cov_kernel<<<BATCH * BLOCKS_PER_BATCH, 256, 0, stream>>>(P, Q, M, ws);
    finalize_kernel<<<BATCH, 256, 0, stream>>>(P, Q, ws, out);
}

// Round 3
// 195.213 us; speedup vs baseline: 1.2772x; 1.0122x over previous
//
#include <hip/hip_runtime.h>

#define BATCH 8
#define NPTS 2048
#define BLOCKS_PER_BATCH 128
#define ROWS_PER_BLOCK 16   // NPTS / BLOCKS_PER_BATCH
#define WS_STRIDE 20        // 18 payload floats padded to 5 x float4

// clang ext_vector (HIP's float4 is a struct; __builtin_nontemporal_load needs a scalar/vector type)
typedef float f4 __attribute__((ext_vector_type(4)));

// ---------------- kernel 1: streaming pass over M (column-accumulation form) ----
// S[d,e] = sum_k P[k,d] * T[k,e],  T[k,e] = sum_n M[n,k] * Q[n,e]
// sum_matched[d] = sum_k P[k,d] * colsum[k]
// Each block owns ROWS_PER_BLOCK rows x all 2048 columns. Thread t owns float4
// column groups {t, t+256}. Zero cross-lane traffic in the hot loop; one
// 18-value block reduction at the end (12 covariance partials + 3 P-col-sums
// + 3 Q-row-sums, so finalize never re-reads P/Q); partials to ws.
// NOTE (R1 post-mortem): do NOT force min-waves via __launch_bounds__(256,8) —
// it capped VGPR at 64, spilled ~235 B/thread (WRITE_SIZE 123 MB, 3.0 TB/s).
// NOTE (R3): hot loop kept at unroll 4 — unroll 8 needs ~130 VGPR, crossing
// the 128-VGPR occupancy cliff (4 -> 2 waves/SIMD) for no MLP benefit.
__global__ void __launch_bounds__(256) cross_cov_kernel(
        const float* __restrict__ P, const float* __restrict__ Q,
        const float* __restrict__ M, float* __restrict__ ws) {
    __shared__ float sQ[ROWS_PER_BLOCK * 3];
    __shared__ float partial[4][18];

    const int b = blockIdx.x >> 7;           // BLOCKS_PER_BATCH = 128
    const int blkInB = blockIdx.x & 127;
    const int n0 = blkInB * ROWS_PER_BLOCK;
    const float* Pb = P + b * NPTS * 3;
    const float* Qb = Q + b * NPTS * 3;
    const float* Mb = M + (size_t)b * NPTS * NPTS;

    const int t = threadIdx.x;
    if (t < ROWS_PER_BLOCK * 3) sQ[t] = Qb[n0 * 3 + t];
    __syncthreads();

    // accumulators: 2 column groups x 4 cols x (T[3] + colsum) = 32 regs
    float T0[4][3] = {}, T1[4][3] = {};
    float cs0[4] = {}, cs1[4] = {};

    const f4* Mrow0 = reinterpret_cast<const f4*>(Mb + (size_t)n0 * NPTS) + t;
    const f4* Mrow1 = Mrow0 + 256;

#pragma unroll 4
    for (int r = 0; r < ROWS_PER_BLOCK; ++r) {
        // M is read exactly once -> non-temporal hint (don't pollute L2/L3)
        const f4 m0 = __builtin_nontemporal_load(Mrow0 + (size_t)r * 512);  // row stride = 2048 f = 512 f4
        const f4 m1 = __builtin_nontemporal_load(Mrow1 + (size_t)r * 512);
        const float q0 = sQ[r * 3 + 0];
        const float q1 = sQ[r * 3 + 1];
        const float q2 = sQ[r * 3 + 2];
        T0[0][0] += m0.x * q0; T0[0][1] += m0.x * q1; T0[0][2] += m0.x * q2; cs0[0] += m0.x;
        T0[1][0] += m0.y * q0; T0[1][1] += m0.y * q1; T0[1][2] += m0.y * q2; cs0[1] += m0.y;
        T0[2][0] += m0.z * q0; T0[2][1] += m0.z * q1; T0[2][2] += m0.z * q2; cs0[2] += m0.z;
        T0[3][0] += m0.w * q0; T0[3][1] += m0.w * q1; T0[3][2] += m0.w * q2; cs0[3] += m0.w;
        T1[0][0] += m1.x * q0; T1[0][1] += m1.x * q1; T1[0][2] += m1.x * q2; cs1[0] += m1.x;
        T1[1][0] += m1.y * q0; T1[1][1] += m1.y * q1; T1[1][2] += m1.y * q2; cs1[1] += m1.y;
        T1[2][0] += m1.z * q0; T1[2][1] += m1.z * q1; T1[2][2] += m1.z * q2; cs1[2] += m1.z;
        T1[3][0] += m1.w * q0; T1[3][1] += m1.w * q1; T1[3][2] += m1.w * q2; cs1[3] += m1.w;
    }

    // acc layout: [0..8] S_raw, [9..11] sum_matched, [12..14] P column sums
    // (every block computes the full-batch P sum -> bit-identical across the
    // 128 blocks; finalize divides by 128, exact), [15..17] this block's
    // 16-row Q sum (sums correctly over blocks).
    float acc[18];
#pragma unroll
    for (int i = 0; i < 18; ++i) acc[i] = 0.0f;
    {
        const int k0 = 4 * t;
        const int k1 = 4 * (t + 256);
        const float* p0 = Pb + k0 * 3;     // 12 consecutive floats, 16B-aligned
        const float* p1 = Pb + k1 * 3;
#pragma unroll
        for (int j = 0; j < 4; ++j) {
            const float pd0 = p0[j * 3 + 0], pd1 = p0[j * 3 + 1], pd2 = p0[j * 3 + 2];
#pragma unroll
            for (int e = 0; e < 3; ++e) {
                acc[0 + e] += pd0 * T0[j][e];
                acc[3 + e] += pd1 * T0[j][e];
                acc[6 + e] += pd2 * T0[j][e];
            }
            acc[9]  += pd0 * cs0[j];
            acc[10] += pd1 * cs0[j];
            acc[11] += pd2 * cs0[j];
            acc[12] += pd0; acc[13] += pd1; acc[14] += pd2;
        }
#pragma unroll
        for (int j = 0; j < 4; ++j) {
            const float pd0 = p1[j * 3 + 0], pd1 = p1[j * 3 + 1], pd2 = p1[j * 3 + 2];
#pragma unroll
            for (int e = 0; e < 3; ++e) {
                acc[0 + e] += pd0 * T1[j][e];
                acc[3 + e] += pd1 * T1[j][e];
                acc[6 + e] += pd2 * T1[j][e];
            }
            acc[9]  += pd0 * cs1[j];
            acc[10] += pd1 * cs1[j];
            acc[11] += pd2 * cs1[j];
            acc[12] += pd0; acc[13] += pd1; acc[14] += pd2;
        }
    }
    // this block's Q-row sums: rows n0..n0+15 live in sQ; lanes 0..15 (wave 0)
    // contribute one row each, the butterfly sums them.
    if (t < ROWS_PER_BLOCK) {
        acc[15] = sQ[t * 3 + 0];
        acc[16] = sQ[t * 3 + 1];
        acc[17] = sQ[t * 3 + 2];
    }

    // block reduction of 18 values: wave butterfly (once per block), then LDS
#pragma unroll
    for (int off = 32; off > 0; off >>= 1) {
#pragma unroll
        for (int i = 0; i < 18; ++i) acc[i] += __shfl_xor(acc[i], off);
    }
    const int wave = t >> 6;
    const int lane = t & 63;
    if (lane == 0) {
#pragma unroll
        for (int i = 0; i < 18; ++i) partial[wave][i] = acc[i];
    }
    __syncthreads();
    if (t < 18) {
        float v = partial[0][t] + partial[1][t] + partial[2][t] + partial[3][t];
        ws[(size_t)blockIdx.x * WS_STRIDE + t] = v;   // per-block partial, no atomics
    }
}

// ---------------- kernel 2: reduce partials + 3x3 polar -> R, t ----------
// Reads ONLY ws (10 KB/batch, L2-hot): P/Q sums were folded into kernel 1.
__global__ void __launch_bounds__(256) finalize_kernel(
        const float* __restrict__ ws, float* __restrict__ out) {
    const int b = blockIdx.x;
    const int t = threadIdx.x;
    const int wave = t >> 6;
    const int lane = t & 63;

    __shared__ float redS[2][18];

    // ---- reduce the 128 per-block partials of this batch (threads 0..127) ----
    if (t < BLOCKS_PER_BATCH) {
        const f4* p4 = reinterpret_cast<const f4*>(
            ws + ((size_t)b * BLOCKS_PER_BATCH + t) * WS_STRIDE);
        f4 a = p4[0], c = p4[1], d = p4[2], e = p4[3], f = p4[4];
        float v[18] = { a.x, a.y, a.z, a.w, c.x, c.y, c.z, c.w,
                        d.x, d.y, d.z, d.w, e.x, e.y, e.z, e.w, f.x, f.y };
#pragma unroll
        for (int off = 32; off > 0; off >>= 1) {
#pragma unroll
            for (int i = 0; i < 18; ++i) v[i] += __shfl_xor(v[i], off);
        }
        if (lane == 0) {
#pragma unroll
            for (int i = 0; i < 18; ++i) redS[wave][i] = v[i];
        }
    }
    __syncthreads();

    if (t == 0) {
        double w[18];
        for (int i = 0; i < 18; ++i) w[i] = (double)redS[0][i] + (double)redS[1][i];

        // P sums were written identically by all 128 blocks: tree-summed 128x,
        // exact power-of-2 multiple -> divide back out exactly.
        const double sp[3] = { w[12] * (1.0 / 128.0), w[13] * (1.0 / 128.0), w[14] * (1.0 / 128.0) };
        const double sq[3] = { w[15], w[16], w[17] };

        // S[d][e] = S_raw[d][e] - sum_matched[d]*sum_Q[e]/N
        double Sm[9];
        for (int d = 0; d < 3; ++d)
            for (int e = 0; e < 3; ++e)
                Sm[d * 3 + e] = w[d * 3 + e] - w[9 + d] * sq[e] / (double)NPTS;

        // R = V U^T = orthogonal polar factor of A = S^T (scaled Newton).
        // 8 iters: scaled Newton hits double eps in ~6 for well-conditioned 3x3;
        // 12 verified bit-stable in R1/R2, 8 keeps >=2 iters of margin.
        double X[9];
        for (int i = 0; i < 3; ++i)
            for (int j = 0; j < 3; ++j)
                X[i * 3 + j] = Sm[j * 3 + i];
        for (int iter = 0; iter < 8; ++iter) {
            double a0 = X[0], a1 = X[1], a2 = X[2];
            double a3 = X[3], a4 = X[4], a5 = X[5];
            double a6 = X[6], a7 = X[7], a8 = X[8];
            double c0 = a4 * a8 - a5 * a7;
            double c1 = a5 * a6 - a3 * a8;
            double c2 = a3 * a7 - a4 * a6;
            double det = a0 * c0 + a1 * c1 + a2 * c2;
            double invdet = 1.0 / det;
            double inv[9];
            inv[0] = c0 * invdet; inv[1] = (a2 * a7 - a1 * a8) * invdet; inv[2] = (a1 * a5 - a2 * a4) * invdet;
            inv[3] = c1 * invdet; inv[4] = (a0 * a8 - a2 * a6) * invdet; inv[5] = (a2 * a3 - a0 * a5) * invdet;
            inv[6] = c2 * invdet; inv[7] = (a1 * a6 - a0 * a7) * invdet; inv[8] = (a0 * a4 - a1 * a3) * invdet;
            double fx = 0, fi = 0;
            for (int i = 0; i < 9; ++i) { fx += X[i] * X[i]; fi += inv[i] * inv[i]; }
            double g = sqrt(sqrt(fi / fx));
            double Xn[9];
            for (int i = 0; i < 3; ++i)
                for (int j = 0; j < 3; ++j)
                    Xn[i * 3 + j] = 0.5 * (g * X[i * 3 + j] + inv[j * 3 + i] / g);
            for (int i = 0; i < 9; ++i) X[i] = Xn[i];
        }
        for (int i = 0; i < 9; ++i) out[b * 9 + i] = (float)X[i];
        const double mpx = sp[0] / NPTS, mpy = sp[1] / NPTS, mpz = sp[2] / NPTS;
        for (int d = 0; d < 3; ++d) {
            double td = sq[d] / NPTS - (X[d * 3 + 0] * mpx + X[d * 3 + 1] * mpy + X[d * 3 + 2] * mpz);
            out[BATCH * 9 + b * 3 + d] = (float)td;
        }
    }
}

extern "C" void kernel_launch(void* const* d_in, const int* in_sizes, int n_in,
                              void* d_out, int out_size, void* d_ws, size_t ws_size,
                              hipStream_t stream) {
    const float* P = (const float*)d_in[0];   // Ppc [8,2048,3] f32
    const float* Q = (const float*)d_in[1];   // Qpc [8,2048,3] f32
    const float* M = (const float*)d_in[2];   // M   [8,2048,2048] f32
    float* out = (float*)d_out;               // R [8,3,3] ++ t [8,3] = 96 f32
    float* ws = (float*)d_ws;                 // per-block partials: 1024*20 f32 = 80 KB

    cross_cov_kernel<<<BATCH * BLOCKS_PER_BATCH, 256, 0, stream>>>(P, Q, M, ws);
    finalize_kernel<<<BATCH, 256, 0, stream>>>(ws, out);
}